// Round 5
// baseline (451.317 us; speedup 1.0000x reference)
//
#include <hip/hip_runtime.h>

#define B_ 2
#define L_ 256
#define H_ 256
#define A_ 32
#define P_ 64
#define PSTR 76    // posT LDS row stride (floats)
#define NPROD 256  // producer blocks (stage A)

typedef __bf16 bf16x8 __attribute__((ext_vector_type(8)));
typedef float  f32x4  __attribute__((ext_vector_type(4)));

// Fused: blocks 0..255 produce h (bf16) and g[r][p][a] (bf16) for rows 2bid..2bid+1,
// then ALL 1024 blocks consume: out[b,i,j,p] = sum_a g[j,a,p] h[i,a] via
// mfma(A=g, B=h) -> D[m=p][n=i], fused bias+pos epilogue, float4 NT stores.
__global__ __launch_bounds__(256, 4) void fused(
    const float* __restrict__ x,     // [B,L,H]
    const float* __restrict__ in_w,  // [A,H]
    const float* __restrict__ in_b,  // [A]
    const float* __restrict__ out_w, // [P, A*A]
    const float* __restrict__ out_b, // [P]
    const float* __restrict__ pos_w, // [P,17]
    const float* __restrict__ pos_b, // [P]
    __bf16* __restrict__ gb,         // [B*L][P][A] bf16 (ws)
    __bf16* __restrict__ hb,         // [B*L][A]   bf16 (ws)
    unsigned int* __restrict__ cnt,  // barrier counter (ws, memset to 0 per call)
    float* __restrict__ out)         // [B,L,L,P]
{
    __shared__ float xs[2 * H_];
    __shared__ float hl[2][A_];
    __shared__ float posT[17 * PSTR];

    const int t = threadIdx.x;
    const int bid = blockIdx.x;

    // ---------------- stage A: producers only ----------------
    if (bid < NPROD) {
        const int r0 = bid * 2;

        if (t < 128) ((float4*)xs)[t] = ((const float4*)(x + (size_t)r0 * H_))[t];
        __syncthreads();

        {   // h: 2 rows x 32 outputs, 4 threads per 256-dot
            const int jj = t >> 7;
            const int rem = t & 127;
            const int a = rem >> 2;
            const int q = rem & 3;
            const float4* w4 = (const float4*)(in_w + a * H_ + q * 64);
            const float4* xv4 = (const float4*)(xs + jj * H_ + q * 64);
            float s = 0.f;
            #pragma unroll
            for (int m = 0; m < 16; ++m) {
                float4 w = w4[m], xv = xv4[m];
                s += w.x * xv.x + w.y * xv.y + w.z * xv.z + w.w * xv.w;
            }
            s += __shfl_xor(s, 1);
            s += __shfl_xor(s, 2);
            if (q == 0) {
                float hv = s + in_b[a];
                hl[jj][a] = hv;
                hb[(r0 + jj) * A_ + a] = (__bf16)hv;
            }
        }
        __syncthreads();

        {   // g: thread owns p = t&63, a-range (t>>6)*8..+7
            const int p = t & 63;
            const int ag = t >> 6;
            float sacc[2][8];
            #pragma unroll
            for (int k = 0; k < 8; ++k) {
                const int a = ag * 8 + k;
                const float4* wrow = (const float4*)(out_w + (size_t)p * (A_ * A_) + a * A_);
                float4 w[8];
                #pragma unroll
                for (int m = 0; m < 8; ++m) w[m] = wrow[m];
                #pragma unroll
                for (int jj = 0; jj < 2; ++jj) {
                    const float4* hh = (const float4*)hl[jj];   // uniform -> broadcast
                    float s = 0.f;
                    #pragma unroll
                    for (int m = 0; m < 8; ++m) {
                        float4 h4 = hh[m];
                        s += w[m].x * h4.x + w[m].y * h4.y + w[m].z * h4.z + w[m].w * h4.w;
                    }
                    sacc[jj][k] = s;
                }
            }
            #pragma unroll
            for (int jj = 0; jj < 2; ++jj) {
                bf16x8 v;
                #pragma unroll
                for (int e = 0; e < 8; ++e) v[e] = (__bf16)sacc[jj][e];
                *(bf16x8*)(gb + ((size_t)((r0 + jj) * P_ + p)) * A_ + ag * 8) = v;
            }
        }

        __syncthreads();   // all producer stores issued & drained (vmcnt0 before barrier)
        if (t == 0) {
            // release at agent scope: L2 writeback so other XCDs see gb/hb
            __hip_atomic_fetch_add(cnt, 1u, __ATOMIC_RELEASE, __HIP_MEMORY_SCOPE_AGENT);
        }
    }

    // ---------------- posT build (overlaps stage A of other blocks) ----------------
    for (int e = t; e < 17 * P_; e += 256) {
        const int d = e >> 6, p = e & 63;
        posT[d * PSTR + p] = pos_w[p * 17 + d] + pos_b[p] + out_b[p];
    }

    // ---------------- barrier: wait for all producers ----------------
    if (t == 0) {
        while (__hip_atomic_load(cnt, __ATOMIC_ACQUIRE, __HIP_MEMORY_SCOPE_AGENT) < NPROD)
            __builtin_amdgcn_s_sleep(2);
    }
    __syncthreads();

    // ---------------- stage B: every block one 16i x 8j x 64p tile ----------------
    const int jt = bid & 31;
    const int it = (bid >> 5) & 15;
    const int b  = bid >> 9;
    const int j0 = jt * 8;
    const int i0 = it * 16;

    const int lane = t & 63;
    const int w = t >> 6;            // wave 0..3
    const int l15 = lane & 15;
    const int hi = lane >> 4;        // 0..3
    const int i = i0 + l15;
    const int p_r0 = hi * 4;

    const bf16x8 hfrag = *(const bf16x8*)(hb + ((size_t)(b * L_ + i)) * A_ + hi * 8);
    const f32x4 zero = {0.f, 0.f, 0.f, 0.f};

    #pragma unroll
    for (int tj = 0; tj < 2; ++tj) {
        const int j = j0 + w * 2 + tj;
        const __bf16* gr = gb + ((size_t)(b * L_ + j)) * (P_ * A_);

        bf16x8 gfrag[4];
        #pragma unroll
        for (int pg = 0; pg < 4; ++pg)
            gfrag[pg] = *(const bf16x8*)(gr + (pg * 16 + l15) * A_ + hi * 8);

        f32x4 acc[4];
        #pragma unroll
        for (int pg = 0; pg < 4; ++pg)
            acc[pg] = __builtin_amdgcn_mfma_f32_16x16x32_bf16(gfrag[pg], hfrag, zero, 0, 0, 0);

        int d = i - j;
        d = d < -8 ? -8 : (d > 8 ? 8 : d);
        d += 8;

        float* op = out + (((size_t)(b * L_ + i)) * L_ + j) * P_;
        #pragma unroll
        for (int pg = 0; pg < 4; ++pg) {
            const f32x4 pe = *(const f32x4*)(posT + d * PSTR + pg * 16 + p_r0);
            __builtin_nontemporal_store(acc[pg] + pe, (f32x4*)(op + pg * 16 + p_r0));
        }
    }
}

extern "C" void kernel_launch(void* const* d_in, const int* in_sizes, int n_in,
                              void* d_out, int out_size, void* d_ws, size_t ws_size,
                              hipStream_t stream) {
    const float* x     = (const float*)d_in[0];
    const float* in_w  = (const float*)d_in[1];
    const float* in_b  = (const float*)d_in[2];
    const float* out_w = (const float*)d_in[3];
    const float* out_b = (const float*)d_in[4];
    const float* pos_w = (const float*)d_in[5];
    const float* pos_b = (const float*)d_in[6];
    float* out = (float*)d_out;

    __bf16* gb = (__bf16*)d_ws;                                   // 2 MB
    __bf16* hb = gb + (size_t)B_ * L_ * P_ * A_;                  // +32 KB
    unsigned int* cnt = (unsigned int*)((char*)d_ws +
        (size_t)B_ * L_ * P_ * A_ * 2 + (size_t)B_ * L_ * A_ * 2);

    hipMemsetAsync(cnt, 0, 4, stream);
    fused<<<dim3(32 * 16 * B_), 256, 0, stream>>>(x, in_w, in_b, out_w, out_b,
                                                  pos_w, pos_b, gb, hb, cnt, out);
}

// Round 6
// 27.994 us; speedup vs baseline: 16.1222x; 16.1222x over previous
//
#include <hip/hip_runtime.h>

#define B_ 2
#define L_ 256
#define H_ 256
#define A_ 32
#define P_ 64
#define PSTR 76    // posT LDS row stride (floats)
#define TSTR 516   // out-tile LDS row stride (floats): 8*64 + 4

typedef __bf16 bf16x8 __attribute__((ext_vector_type(8)));
typedef float  f32x4  __attribute__((ext_vector_type(4)));

// k1: 2 rows per block (256 blocks). h[r,0..31] (f32 in LDS, bf16 to hb),
// g[r,a,p] = sum_c out_w[p, a*32+c] * h[r,c], stored bf16 TRANSPOSED as gb[r][p][a].
__global__ __launch_bounds__(256) void k1_proj(
    const float* __restrict__ x,     // [B,L,H]
    const float* __restrict__ in_w,  // [A,H]
    const float* __restrict__ in_b,  // [A]
    const float* __restrict__ out_w, // [P, A*A]
    __bf16* __restrict__ gb,         // [B*L][P][A] bf16
    __bf16* __restrict__ hb)         // [B*L][A]   bf16
{
    __shared__ float xs[2 * H_];
    __shared__ float hl[2][A_];
    const int t = threadIdx.x;
    const int r0 = blockIdx.x * 2;

    if (t < 128) ((float4*)xs)[t] = ((const float4*)(x + (size_t)r0 * H_))[t];
    __syncthreads();

    {
        const int jj = t >> 7;        // row 0..1
        const int rem = t & 127;
        const int a = rem >> 2;       // 0..31
        const int q = rem & 3;
        const float4* w4 = (const float4*)(in_w + a * H_ + q * 64);
        const float4* xv4 = (const float4*)(xs + jj * H_ + q * 64);
        float s = 0.f;
        #pragma unroll
        for (int m = 0; m < 16; ++m) {
            float4 w = w4[m], xv = xv4[m];
            s += w.x * xv.x + w.y * xv.y + w.z * xv.z + w.w * xv.w;
        }
        s += __shfl_xor(s, 1);
        s += __shfl_xor(s, 2);
        if (q == 0) {
            float hv = s + in_b[a];
            hl[jj][a] = hv;
            hb[(r0 + jj) * A_ + a] = (__bf16)hv;
        }
    }
    __syncthreads();

    const int p = t & 63;
    const int ag = t >> 6;   // 0..3
    float sacc[2][8];
    #pragma unroll
    for (int k = 0; k < 8; ++k) {
        const int a = ag * 8 + k;
        const float4* wrow = (const float4*)(out_w + (size_t)p * (A_ * A_) + a * A_);
        float4 w[8];
        #pragma unroll
        for (int m = 0; m < 8; ++m) w[m] = wrow[m];
        #pragma unroll
        for (int jj = 0; jj < 2; ++jj) {
            const float4* hh = (const float4*)hl[jj];   // uniform -> broadcast
            float s = 0.f;
            #pragma unroll
            for (int m = 0; m < 8; ++m) {
                float4 h4 = hh[m];
                s += w[m].x * h4.x + w[m].y * h4.y + w[m].z * h4.z + w[m].w * h4.w;
            }
            sacc[jj][k] = s;
        }
    }
    #pragma unroll
    for (int jj = 0; jj < 2; ++jj) {
        bf16x8 v;
        #pragma unroll
        for (int e = 0; e < 8; ++e) v[e] = (__bf16)sacc[jj][e];
        *(bf16x8*)(gb + ((size_t)((r0 + jj) * P_ + p)) * A_ + ag * 8) = v;
    }
}

// k2: out[b,i,j,p] = sum_a g[j,a,p] h[i,a] via mfma(A=g, B=h): D[m=p][n=i].
// Tile 16i x 8j x 64p per block. Epilogue: fuse acc+posT into a 33KB LDS tile,
// then linear cooperative NT stores (256B-contiguous per 16-lane group).
__global__ __launch_bounds__(256) void k2_mfma(
    const __bf16* __restrict__ gb,   // [B*L][P][A]
    const __bf16* __restrict__ hb,   // [B*L][A]
    const float* __restrict__ out_b, // [P]
    const float* __restrict__ pos_w, // [P,17]
    const float* __restrict__ pos_b, // [P]
    float* __restrict__ out)         // [B,L,L,P]
{
    __shared__ float posT[17 * PSTR];
    __shared__ float tile[16][TSTR];
    const int t = threadIdx.x;

    for (int e = t; e < 17 * P_; e += 256) {
        const int d = e >> 6, p = e & 63;
        posT[d * PSTR + p] = pos_w[p * 17 + d] + pos_b[p] + out_b[p];
    }
    __syncthreads();

    const int lane = t & 63;
    const int w = t >> 6;            // wave 0..3
    const int j0 = blockIdx.x * 8;
    const int i0 = blockIdx.y * 16;
    const int b = blockIdx.z;

    const int l15 = lane & 15;
    const int hi = lane >> 4;        // 0..3
    const int i = i0 + l15;
    const int p_r0 = hi * 4;         // p offset within 16-p group

    // B-fragment (h): n = i = lane&15, k = hi*8 + e
    const bf16x8 hfrag = *(const bf16x8*)(hb + ((size_t)(b * L_ + i)) * A_ + hi * 8);
    const f32x4 zero = {0.f, 0.f, 0.f, 0.f};

    #pragma unroll
    for (int tj = 0; tj < 2; ++tj) {
        const int jl = w * 2 + tj;   // local j 0..7
        const int j = j0 + jl;
        const __bf16* gr = gb + ((size_t)(b * L_ + j)) * (P_ * A_);

        bf16x8 gfrag[4];
        #pragma unroll
        for (int pg = 0; pg < 4; ++pg)
            gfrag[pg] = *(const bf16x8*)(gr + (pg * 16 + l15) * A_ + hi * 8);

        f32x4 acc[4];
        #pragma unroll
        for (int pg = 0; pg < 4; ++pg)
            acc[pg] = __builtin_amdgcn_mfma_f32_16x16x32_bf16(gfrag[pg], hfrag, zero, 0, 0, 0);

        int d = i - j;
        d = d < -8 ? -8 : (d > 8 ? 8 : d);
        d += 8;

        // fused add + LDS stage: tile[i_local][jl*64 + p]
        #pragma unroll
        for (int pg = 0; pg < 4; ++pg) {
            const f32x4 pe = *(const f32x4*)(posT + d * PSTR + pg * 16 + p_r0);
            *(f32x4*)&tile[l15][jl * 64 + pg * 16 + p_r0] = acc[pg] + pe;
        }
    }
    __syncthreads();

    // linear read-out: row ir has 512 consecutive floats of out
    const int ir = t >> 4;           // 0..15
    const int c  = t & 15;           // 0..15
    float* orow = out + (((size_t)(b * L_ + i0 + ir)) * L_ + j0) * P_;
    #pragma unroll
    for (int m = 0; m < 8; ++m) {
        const int f4 = m * 16 + c;   // 0..127; 16-lane group covers 256B contiguous
        const f32x4 v = *(const f32x4*)&tile[ir][f4 * 4];
        __builtin_nontemporal_store(v, (f32x4*)(orow + f4 * 4));
    }
}

extern "C" void kernel_launch(void* const* d_in, const int* in_sizes, int n_in,
                              void* d_out, int out_size, void* d_ws, size_t ws_size,
                              hipStream_t stream) {
    const float* x     = (const float*)d_in[0];
    const float* in_w  = (const float*)d_in[1];
    const float* in_b  = (const float*)d_in[2];
    const float* out_w = (const float*)d_in[3];
    const float* out_b = (const float*)d_in[4];
    const float* pos_w = (const float*)d_in[5];
    const float* pos_b = (const float*)d_in[6];
    float* out = (float*)d_out;

    __bf16* gb = (__bf16*)d_ws;                                   // 2 MB
    __bf16* hb = gb + (size_t)B_ * L_ * P_ * A_;                  // +32 KB

    k1_proj<<<dim3((B_ * L_) / 2), 256, 0, stream>>>(x, in_w, in_b, out_w, gb, hb);
    k2_mfma<<<dim3(L_ / 8, L_ / 16, B_), 256, 0, stream>>>(gb, hb, out_b, pos_w, pos_b, out);
}